// Round 6
// baseline (901.937 us; speedup 1.0000x reference)
//
#include <hip/hip_runtime.h>
#include <stdint.h>

#define Vn 10242
#define Ln 42
#define LPn 48
#define VPn 10496    /* 41*256 = 82*128 padded rows */
#define RBn 41
#define JPAD 10368   /* 162*64 : j range padded to tile multiple */
#define NITER 5
#define SCL 1.69864360f  /* sqrt(2*log2(e)) : exp(-2 d^2) == exp2(-|SCL*dx|^2) */
#define BR 128

typedef float4 f4;
typedef short bf16x8 __attribute__((ext_vector_type(8)));
typedef float f32x4 __attribute__((ext_vector_type(4)));
typedef unsigned u32x4 __attribute__((ext_vector_type(4)));

__device__ __forceinline__ unsigned cvtpk_bf16(float a, float b) {
    unsigned r;
    asm("v_cvt_pk_bf16_f32 %0, %1, %2" : "=v"(r) : "v"(a), "v"(b));
    return r;  // lo16 = bf16(a), hi16 = bf16(b)
}
__device__ __forceinline__ unsigned short f2bf_rne(float f) {
    unsigned u = __float_as_uint(f);
    u = (u + 0x7fffu + ((u >> 16) & 1u)) >> 16;
    return (unsigned short)u;
}
__device__ __forceinline__ float bf2f(unsigned short h) {
    return __uint_as_float(((unsigned)h) << 16);
}

// ---------------- structure detection: F uniform? S diagonal? diag(S) ----------------
__global__ __launch_bounds__(256) void k_detect(const float* __restrict__ F,
                                                const float* __restrict__ S,
                                                int* flags, float* __restrict__ diagS) {
    int jj = blockIdx.x * 256 + threadIdx.x;          // float2 column index
    if (jj >= Vn / 2) return;
    int j = jj * 2;
    const float c0 = F[0];
    int violF = 0, violS = 0;
    for (int i = blockIdx.y; i < Vn; i += (int)gridDim.y) {
        size_t off = (size_t)i * Vn + j;
        float2 f = *(const float2*)(F + off);
        float2 s = *(const float2*)(S + off);
        violF |= (f.x != c0) | (f.y != c0);
        if (i == j)          { diagS[j] = s.x;     violS |= (s.y != 0.0f); }
        else if (i == j + 1) { diagS[j + 1] = s.y; violS |= (s.x != 0.0f); }
        else                 violS |= (s.x != 0.0f) | (s.y != 0.0f);
    }
    if (violF) atomicOr(&flags[0], 1);
    if (violS) atomicOr(&flags[1], 1);
}

// ---------------- C identity? ----------------
__global__ void k_detC(const float* __restrict__ Cm, int* flags) {
    int viol = 0;
    for (int idx = threadIdx.x; idx < Ln * Ln; idx += 256) {
        int r = idx / Ln, c = idx - r * Ln;
        float expct = (r == c) ? 1.0f : 0.0f;
        viol |= (Cm[idx] != expct);
    }
    if (viol) atomicOr(&flags[3], 1);
}

// ---------------- U, q0 = softmax(U), scaled coords, qT hi/lo bf16; zero pads ----------------
__global__ __launch_bounds__(256) void k_initU(const float* __restrict__ didx,
                                               const float* __restrict__ coords,
                                               float* __restrict__ U, float* __restrict__ qA,
                                               float* __restrict__ qB,
                                               unsigned short* __restrict__ qTAh,
                                               unsigned short* __restrict__ qTAl,
                                               unsigned short* __restrict__ qTBh,
                                               unsigned short* __restrict__ qTBl,
                                               float* __restrict__ xyz) {
    int row = blockIdx.x * 256 + threadIdx.x;   // covers [0, VPn)
    if (row >= Vn) {
        #pragma unroll
        for (int l = 0; l < LPn; ++l) {
            U[(size_t)row * LPn + l] = 0.0f;
            qA[(size_t)row * LPn + l] = 0.0f;
            qB[(size_t)row * LPn + l] = 0.0f;
            qTAh[(size_t)l * VPn + row] = 0;
            qTAl[(size_t)l * VPn + row] = 0;
            qTBh[(size_t)l * VPn + row] = 0;
            qTBl[(size_t)l * VPn + row] = 0;
        }
        *(f4*)(xyz + (size_t)row * 4) = make_float4(0.f, 0.f, 0.f, 0.f);
        return;
    }
    float ux = SCL * coords[(size_t)row * 3 + 0];
    float uy = SCL * coords[(size_t)row * 3 + 1];
    float uz = SCL * coords[(size_t)row * 3 + 2];
    float ss = ux * ux + uy * uy + uz * uz;
    *(f4*)(xyz + (size_t)row * 4) = make_float4(ux, uy, uz, ss);
    float u[Ln];
    float mx = -3.0e38f;
    #pragma unroll
    for (int l = 0; l < Ln; ++l) {
        float x = didx[(size_t)row * Ln + l];
        x = fminf(fmaxf(x, 1e-6f), 1.0f);
        u[l] = __logf(x);
        mx = fmaxf(mx, u[l]);
    }
    float s = 0.0f;
    float e[Ln];
    #pragma unroll
    for (int l = 0; l < Ln; ++l) { e[l] = __expf(u[l] - mx); s += e[l]; }
    float inv = 1.0f / s;
    #pragma unroll
    for (int l = 0; l < Ln; ++l) {
        float qv = e[l] * inv;
        unsigned short h = f2bf_rne(qv);
        U[(size_t)row * LPn + l] = u[l];
        qA[(size_t)row * LPn + l] = qv;
        qTAh[(size_t)l * VPn + row] = h;
        qTAl[(size_t)l * VPn + row] = f2bf_rne(qv - bf2f(h));
    }
    #pragma unroll
    for (int l = Ln; l < LPn; ++l) {
        U[(size_t)row * LPn + l] = 0.0f;
        qA[(size_t)row * LPn + l] = 0.0f;
        qB[(size_t)row * LPn + l] = 0.0f;
        qTAh[(size_t)l * VPn + row] = 0;
        qTAl[(size_t)l * VPn + row] = 0;
        qTBh[(size_t)l * VPn + row] = 0;  // k_B never writes pad labels
        qTBl[(size_t)l * VPn + row] = 0;
    }
}

// ---------------- shared union: fast B-tiles (dbuf) | general W-tile ----------------
union ShPhi {
    struct { uint4 Bh[2][LPn][8]; uint4 Bl[2][LPn][8]; } f;  // 24.6 KB
    float w[256][33];                                         // 33.8 KB
};

// ---------------- general tiled body: partials = (W [*G]) @ X ----------------
template <int USEG>
__device__ __forceinline__ void mat_gen_body(const float* __restrict__ W,
                                             const float* __restrict__ X,
                                             const float* __restrict__ xyz,
                                             float* __restrict__ part, int jchunk,
                                             ShPhi& sh) {
    int t = threadIdx.x;
    int row = blockIdx.x * 256 + t;
    bool act = (row < Vn);
    int j0 = blockIdx.y * jchunk;
    int j1 = j0 + jchunk; if (j1 > Vn) j1 = Vn;
    f4 xi = make_float4(0.f, 0.f, 0.f, 0.f);
    if (USEG && act) xi = *(const f4*)(xyz + (size_t)row * 4);
    f4 acc[12];
    #pragma unroll
    for (int c = 0; c < 12; ++c) acc[c] = make_float4(0.f, 0.f, 0.f, 0.f);
    for (int jt = j0; jt < j1; jt += 32) {
        __syncthreads();
        #pragma unroll
        for (int k = 0; k < 8; ++k) {
            int idx = t + k * 256;
            int r = idx >> 3;
            int cc = (idx & 7) << 2;
            int rr = blockIdx.x * 256 + r;
            int jc = jt + cc;
            float v0 = 0.f, v1 = 0.f, v2 = 0.f, v3 = 0.f;
            if (rr < Vn) {
                const float* wp = W + (size_t)rr * Vn + jc;
                if (jc + 0 < Vn) v0 = wp[0];
                if (jc + 1 < Vn) v1 = wp[1];
                if (jc + 2 < Vn) v2 = wp[2];
                if (jc + 3 < Vn) v3 = wp[3];
            }
            sh.w[r][cc + 0] = v0; sh.w[r][cc + 1] = v1;
            sh.w[r][cc + 2] = v2; sh.w[r][cc + 3] = v3;
        }
        __syncthreads();
        int jend = j1 - jt; if (jend > 32) jend = 32;
        for (int jj = 0; jj < jend; ++jj) {
            int j = jt + jj;
            float f = sh.w[t][jj];
            if (USEG) {
                f4 xj = *(const f4*)(xyz + (size_t)j * 4);
                float dx = xi.x - xj.x, dy = xi.y - xj.y, dz = xi.z - xj.z;
                float t2 = dx * dx; t2 = fmaf(dy, dy, t2); t2 = fmaf(dz, dz, t2);
                float w = exp2f(-t2);
                w = (j == row) ? 0.0f : w;
                f *= w;
            }
            const f4* qr = (const f4*)(X + (size_t)j * LPn);
            #pragma unroll
            for (int c = 0; c < 12; ++c) {
                f4 qv = qr[c];
                acc[c].x = fmaf(f, qv.x, acc[c].x);
                acc[c].y = fmaf(f, qv.y, acc[c].y);
                acc[c].z = fmaf(f, qv.z, acc[c].z);
                acc[c].w = fmaf(f, qv.w, acc[c].w);
            }
        }
    }
    size_t base = (size_t)blockIdx.y * LPn * VPn + row;
    if (act) {
        #pragma unroll
        for (int c = 0; c < 12; ++c) {
            part[base + (size_t)(4 * c + 0) * VPn] = acc[c].x;
            part[base + (size_t)(4 * c + 1) * VPn] = acc[c].y;
            part[base + (size_t)(4 * c + 2) * VPn] = acc[c].z;
            part[base + (size_t)(4 * c + 3) * VPn] = acc[c].w;
        }
    } else if (row < VPn) {
        #pragma unroll
        for (int c = 0; c < LPn; ++c) part[base + (size_t)c * VPn] = 0.0f;
    }
}

// ---------------- filter pass: fast (reg-A MFMA, LDS-B dbuf, 1 barrier/tile) or general ----------------
__global__ __launch_bounds__(256, 4) void k_phi(const unsigned short* __restrict__ qTh,
                                                const unsigned short* __restrict__ qTl,
                                                const f4* __restrict__ xyz4,
                                                const float* __restrict__ Fw,
                                                const float* __restrict__ q,
                                                float* __restrict__ part,
                                                const int* __restrict__ flags,
                                                int jchunkF, int jchunkG) {
    __shared__ ShPhi sh;
    if (flags[0]) {                               // general F path
        if (blockIdx.x >= RBn) return;
        mat_gen_body<1>(Fw, q, (const float*)xyz4, part, jchunkG, sh);
        return;
    }
    const int t = threadIdx.x;
    const int lane = t & 63;
    const int wv = t >> 6;
    const int lo16 = lane & 15, hi4 = lane >> 4;
    const int rowbase = blockIdx.x * BR;
    const int i0 = rowbase + wv * 32 + lo16;      // rs=0 row of this lane
    const int i1 = i0 + 16;                       // rs=1 row
    f4 p0 = xyz4[i0];
    f4 p1 = xyz4[i1];
    const float a0x = 2.f * p0.x, a0y = 2.f * p0.y, a0z = 2.f * p0.z, c0 = -p0.w;
    const float a1x = 2.f * p1.x, a1y = 2.f * p1.y, a1z = 2.f * p1.z, c1 = -p1.w;
    f32x4 acc[2][3];
    #pragma unroll
    for (int rs = 0; rs < 2; ++rs)
        #pragma unroll
        for (int cs = 0; cs < 3; ++cs) acc[rs][cs] = (f32x4){0.f, 0.f, 0.f, 0.f};
    const int j0 = blockIdx.y * jchunkF;
    int j1 = j0 + jchunkF; if (j1 > JPAD) j1 = JPAD;
    const int n0 = t >> 3, sl0 = t & 7;
    const bool two = (t < 128);
    const int n1 = 32 + (t >> 3);                 // valid when two
    uint4 bh0, bl0, bh1, bl1;
    // prologue: load tile 0 and write buf 0
    {
        size_t o0 = (size_t)n0 * VPn + j0 + sl0 * 8;
        bh0 = *(const uint4*)(qTh + o0);
        bl0 = *(const uint4*)(qTl + o0);
        if (two) {
            size_t o1 = (size_t)n1 * VPn + j0 + sl0 * 8;
            bh1 = *(const uint4*)(qTh + o1);
            bl1 = *(const uint4*)(qTl + o1);
        }
        sh.f.Bh[0][n0][sl0 ^ (n0 & 7)] = bh0;
        sh.f.Bl[0][n0][sl0 ^ (n0 & 7)] = bl0;
        if (two) {
            sh.f.Bh[0][n1][sl0 ^ (n1 & 7)] = bh1;
            sh.f.Bl[0][n1][sl0 ^ (n1 & 7)] = bl1;
        }
    }
    int buf = 0;
    for (int jt = j0; jt < j1; jt += 64) {
        // --- global prefetch of next B tile (reads stay within qT's VPn cols) ---
        {
            size_t o0 = (size_t)n0 * VPn + (jt + 64) + sl0 * 8;
            bh0 = *(const uint4*)(qTh + o0);
            bl0 = *(const uint4*)(qTl + o0);
            if (two) {
                size_t o1 = (size_t)n1 * VPn + (jt + 64) + sl0 * 8;
                bh1 = *(const uint4*)(qTh + o1);
                bl1 = *(const uint4*)(qTl + o1);
            }
        }
        // --- w-gen in registers for both K=32 halves of this tile ---
        unsigned AH[2][2][4], AL[2][2][4];        // [kk][rowset][reg]
        #pragma unroll
        for (int kk = 0; kk < 2; ++kk) {
            const int jb = jt + kk * 32 + hi4 * 8;
            float w0[8], w1[8];
            #pragma unroll
            for (int m = 0; m < 8; ++m) {
                f4 xj = xyz4[jb + m];
                w0[m] = exp2f(fmaf(a0z, xj.z, fmaf(a0y, xj.y, fmaf(a0x, xj.x, c0 - xj.w))));
                w1[m] = exp2f(fmaf(a1z, xj.z, fmaf(a1y, xj.y, fmaf(a1x, xj.x, c1 - xj.w))));
            }
            #pragma unroll
            for (int m = 0; m < 4; ++m) {
                unsigned hh0 = cvtpk_bf16(w0[2 * m], w0[2 * m + 1]);
                unsigned hh1 = cvtpk_bf16(w1[2 * m], w1[2 * m + 1]);
                AH[kk][0][m] = hh0;
                AH[kk][1][m] = hh1;
                AL[kk][0][m] = cvtpk_bf16(w0[2 * m]     - __uint_as_float(hh0 << 16),
                                          w0[2 * m + 1] - __uint_as_float(hh0 & 0xffff0000u));
                AL[kk][1][m] = cvtpk_bf16(w1[2 * m]     - __uint_as_float(hh1 << 16),
                                          w1[2 * m + 1] - __uint_as_float(hh1 & 0xffff0000u));
            }
        }
        __syncthreads();                          // single barrier per tile
        // write NEXT tile into the other buffer (no reader until next barrier)
        sh.f.Bh[buf ^ 1][n0][sl0 ^ (n0 & 7)] = bh0;
        sh.f.Bl[buf ^ 1][n0][sl0 ^ (n0 & 7)] = bl0;
        if (two) {
            sh.f.Bh[buf ^ 1][n1][sl0 ^ (n1 & 7)] = bh1;
            sh.f.Bl[buf ^ 1][n1][sl0 ^ (n1 & 7)] = bl1;
        }
        // MFMA on current buffer
        #pragma unroll
        for (int kk = 0; kk < 2; ++kk) {
            union Uu { u32x4 u; bf16x8 v; };
            Uu A0h, A0l, A1h, A1l;
            A0h.u = (u32x4){AH[kk][0][0], AH[kk][0][1], AH[kk][0][2], AH[kk][0][3]};
            A1h.u = (u32x4){AH[kk][1][0], AH[kk][1][1], AH[kk][1][2], AH[kk][1][3]};
            A0l.u = (u32x4){AL[kk][0][0], AL[kk][0][1], AL[kk][0][2], AL[kk][0][3]};
            A1l.u = (u32x4){AL[kk][1][0], AL[kk][1][1], AL[kk][1][2], AL[kk][1][3]};
            #pragma unroll
            for (int cs = 0; cs < 3; ++cs) {
                int n = cs * 16 + lo16;
                int slot = (kk * 4 + hi4) ^ (n & 7);
                bf16x8 bh = *(bf16x8*)&sh.f.Bh[buf][n][slot];
                bf16x8 bl = *(bf16x8*)&sh.f.Bl[buf][n][slot];
                // 3-product double-bf16 (lo*lo dropped, |err| ~2^-18)
                acc[0][cs] = __builtin_amdgcn_mfma_f32_16x16x32_bf16(A0h.v, bh, acc[0][cs], 0, 0, 0);
                acc[0][cs] = __builtin_amdgcn_mfma_f32_16x16x32_bf16(A0h.v, bl, acc[0][cs], 0, 0, 0);
                acc[0][cs] = __builtin_amdgcn_mfma_f32_16x16x32_bf16(A0l.v, bh, acc[0][cs], 0, 0, 0);
                acc[1][cs] = __builtin_amdgcn_mfma_f32_16x16x32_bf16(A1h.v, bh, acc[1][cs], 0, 0, 0);
                acc[1][cs] = __builtin_amdgcn_mfma_f32_16x16x32_bf16(A1h.v, bl, acc[1][cs], 0, 0, 0);
                acc[1][cs] = __builtin_amdgcn_mfma_f32_16x16x32_bf16(A1l.v, bh, acc[1][cs], 0, 0, 0);
            }
        }
        buf ^= 1;
    }
    size_t pb = (size_t)blockIdx.y * LPn * VPn;
    #pragma unroll
    for (int rs = 0; rs < 2; ++rs)
        #pragma unroll
        for (int cs = 0; cs < 3; ++cs) {
            int col = cs * 16 + lo16;
            int row = rowbase + wv * 32 + rs * 16 + hi4 * 4;  // C/D: col=lane&15, row=(lane>>4)*4+reg
            *(f4*)(part + pb + (size_t)col * VPn + row) =
                make_float4(acc[rs][cs][0], acc[rs][cs][1], acc[rs][cs][2], acc[rs][cs][3]);
        }
}

// ---------------- general spatial pass: part = S @ phi ----------------
__global__ __launch_bounds__(256) void k_sp(const float* __restrict__ Sw,
                                            const float* __restrict__ phi,
                                            float* __restrict__ part,
                                            const int* __restrict__ flags, int jchunk) {
    if (!flags[1]) return;
    __shared__ ShPhi sh;
    mat_gen_body<0>(Sw, phi, (const float*)nullptr, part, jchunk, sh);
}

// ---------------- reduce partials -> phi (GENERAL-S path only) ----------------
__global__ __launch_bounds__(256) void k_R0(const float* __restrict__ part,
                                            const unsigned short* __restrict__ qTh,
                                            const unsigned short* __restrict__ qTl,
                                            float* __restrict__ phi,
                                            const int* __restrict__ flags, int NS) {
    if (!flags[1]) return;                        // fast-S: k_B reduces inline
    int tg = blockIdx.x * 256 + threadIdx.x;      // 492*256 == 48 * (VPn/4)
    int c = tg / (VPn / 4);
    int r4 = (tg - c * (VPn / 4)) * 4;
    f4 s = make_float4(0.f, 0.f, 0.f, 0.f);
    for (int n = 0; n < NS; ++n) {
        f4 v = *(const f4*)(part + ((size_t)n * LPn + c) * VPn + r4);
        s.x += v.x; s.y += v.y; s.z += v.z; s.w += v.w;
    }
    if (!flags[0]) {                              // fast-F path included diagonal w=1
        ushort4 h = *(const ushort4*)(qTh + (size_t)c * VPn + r4);
        ushort4 l = *(const ushort4*)(qTl + (size_t)c * VPn + r4);
        s.x -= bf2f(h.x) + bf2f(l.x);
        s.y -= bf2f(h.y) + bf2f(l.y);
        s.z -= bf2f(h.z) + bf2f(l.z);
        s.w -= bf2f(h.w) + bf2f(l.w);
    }
    phi[(size_t)(r4 + 0) * LPn + c] = s.x;
    phi[(size_t)(r4 + 1) * LPn + c] = s.y;
    phi[(size_t)(r4 + 2) * LPn + c] = s.z;
    phi[(size_t)(r4 + 3) * LPn + c] = s.w;
}

// ---------------- epilogue: inline NS-reduce; logits = U + scale*(pt [@C]); softmax ----------------
__global__ __launch_bounds__(256) void k_B(const float* __restrict__ U,
                                           const float* __restrict__ part,
                                           const unsigned short* __restrict__ qTh,
                                           const unsigned short* __restrict__ qTl,
                                           const float* __restrict__ diagS,
                                           const float* __restrict__ Cm,
                                           const float* __restrict__ Fw,
                                           const int* __restrict__ flags,
                                           float* __restrict__ qn,
                                           unsigned short* __restrict__ qTnh,
                                           unsigned short* __restrict__ qTnl,
                                           float* __restrict__ outp, int last, int NS) {
    __shared__ float ldsC[Ln][LPn];
    int t = threadIdx.x;
    if (flags[3]) {
        for (int idx = t; idx < Ln * LPn; idx += 256) {
            int m = idx / LPn, l = idx - m * LPn;
            ldsC[m][l] = (l < Ln) ? Cm[(size_t)m * Ln + l] : 0.0f;
        }
    }
    __syncthreads();
    int row = blockIdx.x * 256 + t;
    if (row >= Vn) return;
    float pt[LPn];
    #pragma unroll
    for (int c = 0; c < LPn; ++c) pt[c] = 0.f;
    for (int n = 0; n < NS; ++n) {
        const float* pn = part + (size_t)n * LPn * VPn + row;
        #pragma unroll
        for (int c = 0; c < LPn; ++c) pt[c] += pn[(size_t)c * VPn];
    }
    if (!flags[0] && !flags[1]) {                 // fast F + diagonal S: remove diagonal term
        #pragma unroll
        for (int c = 0; c < LPn; ++c)
            pt[c] -= bf2f(qTh[(size_t)c * VPn + row]) + bf2f(qTl[(size_t)c * VPn + row]);
    }
    float scale = (flags[0] ? 1.0f : Fw[0]) * (flags[1] ? 1.0f : diagS[row]);
    float ph[LPn];
    if (flags[3]) {
        #pragma unroll
        for (int c = 0; c < LPn; ++c) ph[c] = 0.f;
        #pragma unroll
        for (int m = 0; m < Ln; ++m) {
            float pm = pt[m];
            #pragma unroll
            for (int c = 0; c < 12; ++c) {
                f4 cv = *(const f4*)&ldsC[m][4 * c];
                ph[4 * c + 0] = fmaf(pm, cv.x, ph[4 * c + 0]);
                ph[4 * c + 1] = fmaf(pm, cv.y, ph[4 * c + 1]);
                ph[4 * c + 2] = fmaf(pm, cv.z, ph[4 * c + 2]);
                ph[4 * c + 3] = fmaf(pm, cv.w, ph[4 * c + 3]);
            }
        }
    } else {
        #pragma unroll
        for (int c = 0; c < LPn; ++c) ph[c] = pt[c];
    }
    float lg[LPn];
    #pragma unroll
    for (int c = 0; c < 12; ++c) {
        f4 uv = *(const f4*)(U + (size_t)row * LPn + 4 * c);
        lg[4 * c + 0] = uv.x + scale * ph[4 * c + 0];
        lg[4 * c + 1] = uv.y + scale * ph[4 * c + 1];
        lg[4 * c + 2] = uv.z + scale * ph[4 * c + 2];
        lg[4 * c + 3] = uv.w + scale * ph[4 * c + 3];
    }
    float mx = lg[0];
    #pragma unroll
    for (int l = 1; l < Ln; ++l) mx = fmaxf(mx, lg[l]);
    float s = 0.f;
    float e[LPn];
    #pragma unroll
    for (int l = 0; l < Ln; ++l) { e[l] = __expf(lg[l] - mx); s += e[l]; }
    #pragma unroll
    for (int l = Ln; l < LPn; ++l) e[l] = 0.f;
    float inv = 1.0f / s;
    #pragma unroll
    for (int c = 0; c < 12; ++c) {
        f4 v = make_float4(e[4 * c + 0] * inv, e[4 * c + 1] * inv,
                           e[4 * c + 2] * inv, e[4 * c + 3] * inv);
        *(f4*)(qn + (size_t)row * LPn + 4 * c) = v;
    }
    #pragma unroll
    for (int l = 0; l < Ln; ++l) {
        float qv = e[l] * inv;
        unsigned short h = f2bf_rne(qv);
        qTnh[(size_t)l * VPn + row] = h;
        qTnl[(size_t)l * VPn + row] = f2bf_rne(qv - bf2f(h));
    }
    if (last) {
        #pragma unroll
        for (int l = 0; l < Ln; ++l) outp[(size_t)row * Ln + l] = e[l] * inv;
    }
}

// ---------------- host launcher ----------------
extern "C" void kernel_launch(void* const* d_in, const int* in_sizes, int n_in,
                              void* d_out, int out_size, void* d_ws, size_t ws_size,
                              hipStream_t stream) {
    const float* didx   = (const float*)d_in[0];
    const float* coords = (const float*)d_in[1];
    const float* Fw     = (const float*)d_in[2];
    const float* Sw     = (const float*)d_in[3];
    const float* Cm     = (const float*)d_in[4];
    float* outp = (float*)d_out;
    float* wsf = (float*)d_ws;

    int*   flags = (int*)wsf;                           // 16 floats reserved
    float* diagS = wsf + 16;                            // VPn
    float* xyz   = diagS + VPn;                         // VPn*4
    float* U     = xyz + (size_t)VPn * 4;               // VPn*48
    float* qA    = U + (size_t)VPn * LPn;
    float* qB    = qA + (size_t)VPn * LPn;
    float* phi   = qB + (size_t)VPn * LPn;
    unsigned short* qTAh = (unsigned short*)(phi + (size_t)VPn * LPn);
    unsigned short* qTAl = qTAh + (size_t)LPn * VPn;
    unsigned short* qTBh = qTAl + (size_t)LPn * VPn;
    unsigned short* qTBl = qTBh + (size_t)LPn * VPn;
    float* part  = (float*)(qTBl + (size_t)LPn * VPn);  // NS*48*VPn

    size_t base_f = 16 + (size_t)VPn * (1 + 4) + (size_t)VPn * LPn * 4 + (size_t)VPn * LPn * 2;
    int NS = 12;
    while (NS > 1 && (base_f + (size_t)NS * LPn * VPn) * 4 > ws_size) NS--;
    int jchunkF = (((JPAD / 64) + NS - 1) / NS) * 64;
    int jchunkG = (((Vn + NS - 1) / NS) + 31) & ~31;

    hipMemsetAsync(flags, 0, 16, stream);
    hipLaunchKernelGGL(k_detect, dim3((Vn / 2 + 255) / 256, 1024), dim3(256), 0, stream,
                       Fw, Sw, flags, diagS);
    hipLaunchKernelGGL(k_detC, dim3(1), dim3(256), 0, stream, Cm, flags);
    hipLaunchKernelGGL(k_initU, dim3(RBn), dim3(256), 0, stream,
                       didx, coords, U, qA, qB, qTAh, qTAl, qTBh, qTBl, xyz);

    float* qcur = qA;  float* qnxt = qB;
    unsigned short* qThc = qTAh;  unsigned short* qTlc = qTAl;
    unsigned short* qThn = qTBh;  unsigned short* qTln = qTBl;
    for (int it = 0; it < NITER; ++it) {
        hipLaunchKernelGGL(k_phi, dim3(VPn / BR, NS), dim3(256), 0, stream,
                           qThc, qTlc, (const f4*)xyz, Fw, qcur, part, flags,
                           jchunkF, jchunkG);
        hipLaunchKernelGGL(k_R0, dim3(LPn * (VPn / 4) / 256), dim3(256), 0, stream,
                           part, qThc, qTlc, phi, flags, NS);
        hipLaunchKernelGGL(k_sp, dim3(RBn, NS), dim3(256), 0, stream,
                           Sw, phi, part, flags, jchunkG);
        hipLaunchKernelGGL(k_B, dim3(RBn), dim3(256), 0, stream,
                           U, part, qThc, qTlc, diagS, Cm, Fw, flags,
                           qnxt, qThn, qTln, outp, (it == NITER - 1) ? 1 : 0, NS);
        float* tq = qcur; qcur = qnxt; qnxt = tq;
        unsigned short* th = qThc; qThc = qThn; qThn = th;
        unsigned short* tl = qTlc; qTlc = qTln; qTln = tl;
    }
}

// Round 7
// 589.634 us; speedup vs baseline: 1.5297x; 1.5297x over previous
//
#include <hip/hip_runtime.h>
#include <stdint.h>

#define Vn 10242
#define Ln 42
#define LPn 48
#define VPn 10496    /* 41*256 = 82*128 padded rows */
#define RBn 41
#define JPAD 10368   /* 162*64 : j range padded to K-tile multiple */
#define NITER 5
#define SCL 1.69864360f  /* sqrt(2*log2(e)) : exp(-2 d^2) == exp2(-|SCL*dx|^2) */
#define BR 128

typedef float4 f4;
typedef short bf16x8 __attribute__((ext_vector_type(8)));
typedef float f32x4 __attribute__((ext_vector_type(4)));

__device__ __forceinline__ unsigned cvtpk_bf16(float a, float b) {
    unsigned r;
    asm("v_cvt_pk_bf16_f32 %0, %1, %2" : "=v"(r) : "v"(a), "v"(b));
    return r;  // lo16 = bf16(a), hi16 = bf16(b)
}
__device__ __forceinline__ unsigned short f2bf_rne(float f) {
    unsigned u = __float_as_uint(f);
    u = (u + 0x7fffu + ((u >> 16) & 1u)) >> 16;
    return (unsigned short)u;
}
__device__ __forceinline__ float bf2f(unsigned short h) {
    return __uint_as_float(((unsigned)h) << 16);
}

// ---------------- structure detection: F uniform? S diagonal? diag(S) ----------------
__global__ __launch_bounds__(256) void k_detect(const float* __restrict__ F,
                                                const float* __restrict__ S,
                                                int* flags, float* __restrict__ diagS) {
    int jj = blockIdx.x * 256 + threadIdx.x;          // float2 column index
    if (jj >= Vn / 2) return;
    int j = jj * 2;
    const float c0 = F[0];
    int violF = 0, violS = 0;
    for (int i = blockIdx.y; i < Vn; i += (int)gridDim.y) {
        size_t off = (size_t)i * Vn + j;
        float2 f = *(const float2*)(F + off);
        float2 s = *(const float2*)(S + off);
        violF |= (f.x != c0) | (f.y != c0);
        if (i == j)          { diagS[j] = s.x;     violS |= (s.y != 0.0f); }
        else if (i == j + 1) { diagS[j + 1] = s.y; violS |= (s.x != 0.0f); }
        else                 violS |= (s.x != 0.0f) | (s.y != 0.0f);
    }
    if (violF) atomicOr(&flags[0], 1);
    if (violS) atomicOr(&flags[1], 1);
}

// ---------------- C identity? ----------------
__global__ void k_detC(const float* __restrict__ Cm, int* flags) {
    int viol = 0;
    for (int idx = threadIdx.x; idx < Ln * Ln; idx += 256) {
        int r = idx / Ln, c = idx - r * Ln;
        float expct = (r == c) ? 1.0f : 0.0f;
        viol |= (Cm[idx] != expct);
    }
    if (viol) atomicOr(&flags[3], 1);
}

// ---------------- U, q0 = softmax(U), scaled coords, qT hi/lo bf16; zero pads ----------------
__global__ __launch_bounds__(256) void k_initU(const float* __restrict__ didx,
                                               const float* __restrict__ coords,
                                               float* __restrict__ U, float* __restrict__ qA,
                                               float* __restrict__ qB,
                                               unsigned short* __restrict__ qTAh,
                                               unsigned short* __restrict__ qTAl,
                                               unsigned short* __restrict__ qTBh,
                                               unsigned short* __restrict__ qTBl,
                                               float* __restrict__ xyz) {
    int row = blockIdx.x * 256 + threadIdx.x;   // covers [0, VPn)
    if (row >= Vn) {
        #pragma unroll
        for (int l = 0; l < LPn; ++l) {
            U[(size_t)row * LPn + l] = 0.0f;
            qA[(size_t)row * LPn + l] = 0.0f;
            qB[(size_t)row * LPn + l] = 0.0f;
            qTAh[(size_t)l * VPn + row] = 0;
            qTAl[(size_t)l * VPn + row] = 0;
            qTBh[(size_t)l * VPn + row] = 0;
            qTBl[(size_t)l * VPn + row] = 0;
        }
        *(f4*)(xyz + (size_t)row * 4) = make_float4(0.f, 0.f, 0.f, 0.f);
        return;
    }
    float ux = SCL * coords[(size_t)row * 3 + 0];
    float uy = SCL * coords[(size_t)row * 3 + 1];
    float uz = SCL * coords[(size_t)row * 3 + 2];
    float ss = ux * ux + uy * uy + uz * uz;
    *(f4*)(xyz + (size_t)row * 4) = make_float4(ux, uy, uz, ss);
    float u[Ln];
    float mx = -3.0e38f;
    #pragma unroll
    for (int l = 0; l < Ln; ++l) {
        float x = didx[(size_t)row * Ln + l];
        x = fminf(fmaxf(x, 1e-6f), 1.0f);
        u[l] = __logf(x);
        mx = fmaxf(mx, u[l]);
    }
    float s = 0.0f;
    float e[Ln];
    #pragma unroll
    for (int l = 0; l < Ln; ++l) { e[l] = __expf(u[l] - mx); s += e[l]; }
    float inv = 1.0f / s;
    #pragma unroll
    for (int l = 0; l < Ln; ++l) {
        float qv = e[l] * inv;
        unsigned short h = f2bf_rne(qv);
        U[(size_t)row * LPn + l] = u[l];
        qA[(size_t)row * LPn + l] = qv;
        qTAh[(size_t)l * VPn + row] = h;
        qTAl[(size_t)l * VPn + row] = f2bf_rne(qv - bf2f(h));
    }
    #pragma unroll
    for (int l = Ln; l < LPn; ++l) {
        U[(size_t)row * LPn + l] = 0.0f;
        qA[(size_t)row * LPn + l] = 0.0f;
        qB[(size_t)row * LPn + l] = 0.0f;
        qTAh[(size_t)l * VPn + row] = 0;
        qTAl[(size_t)l * VPn + row] = 0;
        qTBh[(size_t)l * VPn + row] = 0;  // k_B never writes pad labels
        qTBl[(size_t)l * VPn + row] = 0;
    }
}

// ---------------- shared union: fast A/B tiles | general W tile ----------------
union ShPhi {
    struct {
        uint4 Ah[8][BR];      // 16 KB
        uint4 Al[8][BR];      // 16 KB
        uint4 Bh[LPn][8];     // 6 KB
        uint4 Bl[LPn][8];     // 6 KB
    } f;
    float w[256][33];         // 33.8 KB (general path)
};

// ---------------- general tiled body: partials = (W [*G]) @ X ----------------
template <int USEG>
__device__ __forceinline__ void mat_gen_body(const float* __restrict__ W,
                                             const float* __restrict__ X,
                                             const float* __restrict__ xyz,
                                             float* __restrict__ part, int jchunk,
                                             ShPhi& sh) {
    int t = threadIdx.x;
    int row = blockIdx.x * 256 + t;
    bool act = (row < Vn);
    int j0 = blockIdx.y * jchunk;
    int j1 = j0 + jchunk; if (j1 > Vn) j1 = Vn;
    f4 xi = make_float4(0.f, 0.f, 0.f, 0.f);
    if (USEG && act) xi = *(const f4*)(xyz + (size_t)row * 4);
    f4 acc[12];
    #pragma unroll
    for (int c = 0; c < 12; ++c) acc[c] = make_float4(0.f, 0.f, 0.f, 0.f);
    for (int jt = j0; jt < j1; jt += 32) {
        __syncthreads();
        #pragma unroll
        for (int k = 0; k < 8; ++k) {
            int idx = t + k * 256;
            int r = idx >> 3;
            int cc = (idx & 7) << 2;
            int rr = blockIdx.x * 256 + r;
            int jc = jt + cc;
            float v0 = 0.f, v1 = 0.f, v2 = 0.f, v3 = 0.f;
            if (rr < Vn) {
                const float* wp = W + (size_t)rr * Vn + jc;
                if (jc + 0 < Vn) v0 = wp[0];
                if (jc + 1 < Vn) v1 = wp[1];
                if (jc + 2 < Vn) v2 = wp[2];
                if (jc + 3 < Vn) v3 = wp[3];
            }
            sh.w[r][cc + 0] = v0; sh.w[r][cc + 1] = v1;
            sh.w[r][cc + 2] = v2; sh.w[r][cc + 3] = v3;
        }
        __syncthreads();
        int jend = j1 - jt; if (jend > 32) jend = 32;
        for (int jj = 0; jj < jend; ++jj) {
            int j = jt + jj;
            float f = sh.w[t][jj];
            if (USEG) {
                f4 xj = *(const f4*)(xyz + (size_t)j * 4);
                float dx = xi.x - xj.x, dy = xi.y - xj.y, dz = xi.z - xj.z;
                float t2 = dx * dx; t2 = fmaf(dy, dy, t2); t2 = fmaf(dz, dz, t2);
                float w = exp2f(-t2);
                w = (j == row) ? 0.0f : w;
                f *= w;
            }
            const f4* qr = (const f4*)(X + (size_t)j * LPn);
            #pragma unroll
            for (int c = 0; c < 12; ++c) {
                f4 qv = qr[c];
                acc[c].x = fmaf(f, qv.x, acc[c].x);
                acc[c].y = fmaf(f, qv.y, acc[c].y);
                acc[c].z = fmaf(f, qv.z, acc[c].z);
                acc[c].w = fmaf(f, qv.w, acc[c].w);
            }
        }
    }
    size_t base = (size_t)blockIdx.y * LPn * VPn + row;
    if (act) {
        #pragma unroll
        for (int c = 0; c < 12; ++c) {
            part[base + (size_t)(4 * c + 0) * VPn] = acc[c].x;
            part[base + (size_t)(4 * c + 1) * VPn] = acc[c].y;
            part[base + (size_t)(4 * c + 2) * VPn] = acc[c].z;
            part[base + (size_t)(4 * c + 3) * VPn] = acc[c].w;
        }
    } else if (row < VPn) {
        #pragma unroll
        for (int c = 0; c < LPn; ++c) part[base + (size_t)c * VPn] = 0.0f;
    }
}

// ---------------- filter pass: fast (r4 structure, 3-product) or general ----------------
__global__ __launch_bounds__(256, 3) void k_phi(const unsigned short* __restrict__ qTh,
                                                const unsigned short* __restrict__ qTl,
                                                const f4* __restrict__ xyz4,
                                                const float* __restrict__ Fw,
                                                const float* __restrict__ q,
                                                float* __restrict__ part,
                                                const int* __restrict__ flags,
                                                int jchunkF, int jchunkG) {
    __shared__ ShPhi sh;
    if (flags[0]) {                               // general F path
        if (blockIdx.x >= RBn) return;
        mat_gen_body<1>(Fw, q, (const float*)xyz4, part, jchunkG, sh);
        return;
    }
    const int t = threadIdx.x;
    const int lane = t & 63;
    const int wv = t >> 6;
    const int lo16 = lane & 15, hi4 = lane >> 4;
    const int rowbase = blockIdx.x * BR;
    f4 p0 = xyz4[rowbase + lane];
    f4 p1 = xyz4[rowbase + lane + 64];
    const float v0x = 2.f * p0.x, v0y = 2.f * p0.y, v0z = 2.f * p0.z, ns0 = -p0.w;
    const float v1x = 2.f * p1.x, v1y = 2.f * p1.y, v1z = 2.f * p1.z, ns1 = -p1.w;
    f32x4 acc[2][3];
    #pragma unroll
    for (int rs = 0; rs < 2; ++rs)
        #pragma unroll
        for (int cs = 0; cs < 3; ++cs) acc[rs][cs] = (f32x4){0.f, 0.f, 0.f, 0.f};
    const int j0 = blockIdx.y * jchunkF;
    int j1 = j0 + jchunkF; if (j1 > JPAD) j1 = JPAD;
    const int n0 = t >> 3, sl0 = t & 7;
    const int s1 = t + 256;
    const int n1 = s1 >> 3, sl1 = s1 & 7;
    const bool has1 = (s1 < LPn * 8);
    for (int jt = j0; jt < j1; jt += 64) {
        // --- B-tile prefetch into regs (latency hides under w-gen) ---
        uint4 bh0 = *(const uint4*)(qTh + (size_t)n0 * VPn + jt + sl0 * 8);
        uint4 bl0 = *(const uint4*)(qTl + (size_t)n0 * VPn + jt + sl0 * 8);
        uint4 bh1, bl1;
        if (has1) {
            bh1 = *(const uint4*)(qTh + (size_t)n1 * VPn + jt + sl1 * 8);
            bl1 = *(const uint4*)(qTl + (size_t)n1 * VPn + jt + sl1 * 8);
        }
        // --- w-gen: wave wv computes j in [jt+wv*16, +16) for rows lane, lane+64 ---
        const int jb = __builtin_amdgcn_readfirstlane(jt + wv * 16);
        unsigned ph0[8], ph1[8], pl0[8], pl1[8];
        #pragma unroll
        for (int m = 0; m < 16; m += 2) {
            f4 qa = xyz4[jb + m];       // wave-uniform -> scalar load
            f4 qb = xyz4[jb + m + 1];
            float wa0 = exp2f(fmaf(v0z, qa.z, fmaf(v0y, qa.y, fmaf(v0x, qa.x, ns0 - qa.w))));
            float wb0 = exp2f(fmaf(v0z, qb.z, fmaf(v0y, qb.y, fmaf(v0x, qb.x, ns0 - qb.w))));
            float wa1 = exp2f(fmaf(v1z, qa.z, fmaf(v1y, qa.y, fmaf(v1x, qa.x, ns1 - qa.w))));
            float wb1 = exp2f(fmaf(v1z, qb.z, fmaf(v1y, qb.y, fmaf(v1x, qb.x, ns1 - qb.w))));
            unsigned h0 = cvtpk_bf16(wa0, wb0);
            unsigned h1 = cvtpk_bf16(wa1, wb1);
            ph0[m >> 1] = h0;
            ph1[m >> 1] = h1;
            pl0[m >> 1] = cvtpk_bf16(wa0 - __uint_as_float(h0 << 16),
                                     wb0 - __uint_as_float(h0 & 0xffff0000u));
            pl1[m >> 1] = cvtpk_bf16(wa1 - __uint_as_float(h1 << 16),
                                     wb1 - __uint_as_float(h1 & 0xffff0000u));
        }
        __syncthreads();   // previous tile's LDS reads done
        sh.f.Ah[2 * wv][lane]          = make_uint4(ph0[0], ph0[1], ph0[2], ph0[3]);
        sh.f.Ah[2 * wv + 1][lane]      = make_uint4(ph0[4], ph0[5], ph0[6], ph0[7]);
        sh.f.Ah[2 * wv][lane + 64]     = make_uint4(ph1[0], ph1[1], ph1[2], ph1[3]);
        sh.f.Ah[2 * wv + 1][lane + 64] = make_uint4(ph1[4], ph1[5], ph1[6], ph1[7]);
        sh.f.Al[2 * wv][lane]          = make_uint4(pl0[0], pl0[1], pl0[2], pl0[3]);
        sh.f.Al[2 * wv + 1][lane]      = make_uint4(pl0[4], pl0[5], pl0[6], pl0[7]);
        sh.f.Al[2 * wv][lane + 64]     = make_uint4(pl1[0], pl1[1], pl1[2], pl1[3]);
        sh.f.Al[2 * wv + 1][lane + 64] = make_uint4(pl1[4], pl1[5], pl1[6], pl1[7]);
        sh.f.Bh[n0][sl0 ^ (n0 & 7)] = bh0;
        sh.f.Bl[n0][sl0 ^ (n0 & 7)] = bl0;
        if (has1) {
            sh.f.Bh[n1][sl1 ^ (n1 & 7)] = bh1;
            sh.f.Bl[n1][sl1 ^ (n1 & 7)] = bl1;
        }
        __syncthreads();   // tiles ready
        #pragma unroll
        for (int kk = 0; kk < 2; ++kk) {
            bf16x8 a0h = *(bf16x8*)&sh.f.Ah[kk * 4 + hi4][wv * 32 + lo16];
            bf16x8 a1h = *(bf16x8*)&sh.f.Ah[kk * 4 + hi4][wv * 32 + 16 + lo16];
            bf16x8 a0l = *(bf16x8*)&sh.f.Al[kk * 4 + hi4][wv * 32 + lo16];
            bf16x8 a1l = *(bf16x8*)&sh.f.Al[kk * 4 + hi4][wv * 32 + 16 + lo16];
            #pragma unroll
            for (int cs = 0; cs < 3; ++cs) {
                int n = cs * 16 + lo16;
                int slot = (kk * 4 + hi4) ^ (n & 7);
                bf16x8 bh = *(bf16x8*)&sh.f.Bh[n][slot];
                bf16x8 bl = *(bf16x8*)&sh.f.Bl[n][slot];
                // 3-product double-bf16 (lo*lo dropped: |err| ~2^-18)
                acc[0][cs] = __builtin_amdgcn_mfma_f32_16x16x32_bf16(a0h, bh, acc[0][cs], 0, 0, 0);
                acc[0][cs] = __builtin_amdgcn_mfma_f32_16x16x32_bf16(a0h, bl, acc[0][cs], 0, 0, 0);
                acc[0][cs] = __builtin_amdgcn_mfma_f32_16x16x32_bf16(a0l, bh, acc[0][cs], 0, 0, 0);
                acc[1][cs] = __builtin_amdgcn_mfma_f32_16x16x32_bf16(a1h, bh, acc[1][cs], 0, 0, 0);
                acc[1][cs] = __builtin_amdgcn_mfma_f32_16x16x32_bf16(a1h, bl, acc[1][cs], 0, 0, 0);
                acc[1][cs] = __builtin_amdgcn_mfma_f32_16x16x32_bf16(a1l, bh, acc[1][cs], 0, 0, 0);
            }
        }
    }
    size_t pb = (size_t)blockIdx.y * LPn * VPn;
    #pragma unroll
    for (int rs = 0; rs < 2; ++rs)
        #pragma unroll
        for (int cs = 0; cs < 3; ++cs) {
            int col = cs * 16 + lo16;
            int row = rowbase + wv * 32 + rs * 16 + hi4 * 4;
            *(f4*)(part + pb + (size_t)col * VPn + row) =
                make_float4(acc[rs][cs][0], acc[rs][cs][1], acc[rs][cs][2], acc[rs][cs][3]);
        }
}

// ---------------- general spatial pass: part = S @ phi ----------------
__global__ __launch_bounds__(256) void k_sp(const float* __restrict__ Sw,
                                            const float* __restrict__ phi,
                                            float* __restrict__ part,
                                            const int* __restrict__ flags, int jchunk) {
    if (!flags[1]) return;
    __shared__ ShPhi sh;
    mat_gen_body<0>(Sw, phi, (const float*)nullptr, part, jchunk, sh);
}

// ---------------- reduce partials -> phi [row][48]; bf16-exact diagonal subtract ----------------
__global__ __launch_bounds__(256) void k_R0(const float* __restrict__ part,
                                            const unsigned short* __restrict__ qTh,
                                            const unsigned short* __restrict__ qTl,
                                            float* __restrict__ phi,
                                            const int* __restrict__ flags,
                                            int NS, int gate) {
    if (gate && !flags[1]) return;
    int tg = blockIdx.x * 256 + threadIdx.x;       // 492*256 == 48 * (VPn/4)
    int c = tg / (VPn / 4);
    int r4 = (tg - c * (VPn / 4)) * 4;
    f4 s = make_float4(0.f, 0.f, 0.f, 0.f);
    for (int n = 0; n < NS; ++n) {
        f4 v = *(const f4*)(part + ((size_t)n * LPn + c) * VPn + r4);
        s.x += v.x; s.y += v.y; s.z += v.z; s.w += v.w;
    }
    if (!gate && !flags[0]) {                      // MFMA path included diagonal w=1
        ushort4 h = *(const ushort4*)(qTh + (size_t)c * VPn + r4);
        ushort4 l = *(const ushort4*)(qTl + (size_t)c * VPn + r4);
        s.x -= bf2f(h.x) + bf2f(l.x);
        s.y -= bf2f(h.y) + bf2f(l.y);
        s.z -= bf2f(h.z) + bf2f(l.z);
        s.w -= bf2f(h.w) + bf2f(l.w);
    }
    phi[(size_t)(r4 + 0) * LPn + c] = s.x;
    phi[(size_t)(r4 + 1) * LPn + c] = s.y;
    phi[(size_t)(r4 + 2) * LPn + c] = s.z;
    phi[(size_t)(r4 + 3) * LPn + c] = s.w;
}

// ---------------- epilogue: logits = U + scale*(pt [@C]); q = softmax; emit q + qT hi/lo ----------------
__global__ __launch_bounds__(256) void k_B(const float* __restrict__ U,
                                           const float* __restrict__ phi,
                                           const float* __restrict__ phi2,
                                           const float* __restrict__ diagS,
                                           const float* __restrict__ Cm,
                                           const float* __restrict__ Fw,
                                           const int* __restrict__ flags,
                                           float* __restrict__ qn,
                                           unsigned short* __restrict__ qTnh,
                                           unsigned short* __restrict__ qTnl,
                                           float* __restrict__ outp, int last) {
    __shared__ float ldsC[Ln][LPn];
    int t = threadIdx.x;
    if (flags[3]) {
        for (int idx = t; idx < Ln * LPn; idx += 256) {
            int m = idx / LPn, l = idx - m * LPn;
            ldsC[m][l] = (l < Ln) ? Cm[(size_t)m * Ln + l] : 0.0f;
        }
    }
    __syncthreads();
    int row = blockIdx.x * 256 + t;
    if (row >= Vn) return;
    const float* src = flags[1] ? phi2 : phi;
    float pt[LPn];
    #pragma unroll
    for (int c = 0; c < 12; ++c) {
        f4 v = *(const f4*)(src + (size_t)row * LPn + 4 * c);
        pt[4 * c + 0] = v.x; pt[4 * c + 1] = v.y;
        pt[4 * c + 2] = v.z; pt[4 * c + 3] = v.w;
    }
    float scale = (flags[0] ? 1.0f : Fw[0]) * (flags[1] ? 1.0f : diagS[row]);
    float ph[LPn];
    if (flags[3]) {
        #pragma unroll
        for (int c = 0; c < LPn; ++c) ph[c] = 0.f;
        #pragma unroll
        for (int m = 0; m < Ln; ++m) {
            float pm = pt[m];
            #pragma unroll
            for (int c = 0; c < 12; ++c) {
                f4 cv = *(const f4*)&ldsC[m][4 * c];
                ph[4 * c + 0] = fmaf(pm, cv.x, ph[4 * c + 0]);
                ph[4 * c + 1] = fmaf(pm, cv.y, ph[4 * c + 1]);
                ph[4 * c + 2] = fmaf(pm, cv.z, ph[4 * c + 2]);
                ph[4 * c + 3] = fmaf(pm, cv.w, ph[4 * c + 3]);
            }
        }
    } else {
        #pragma unroll
        for (int c = 0; c < LPn; ++c) ph[c] = pt[c];
    }
    float lg[LPn];
    #pragma unroll
    for (int c = 0; c < 12; ++c) {
        f4 uv = *(const f4*)(U + (size_t)row * LPn + 4 * c);
        lg[4 * c + 0] = uv.x + scale * ph[4 * c + 0];
        lg[4 * c + 1] = uv.y + scale * ph[4 * c + 1];
        lg[4 * c + 2] = uv.z + scale * ph[4 * c + 2];
        lg[4 * c + 3] = uv.w + scale * ph[4 * c + 3];
    }
    float mx = lg[0];
    #pragma unroll
    for (int l = 1; l < Ln; ++l) mx = fmaxf(mx, lg[l]);
    float s = 0.f;
    float e[LPn];
    #pragma unroll
    for (int l = 0; l < Ln; ++l) { e[l] = __expf(lg[l] - mx); s += e[l]; }
    #pragma unroll
    for (int l = Ln; l < LPn; ++l) e[l] = 0.f;
    float inv = 1.0f / s;
    #pragma unroll
    for (int c = 0; c < 12; ++c) {
        f4 v = make_float4(e[4 * c + 0] * inv, e[4 * c + 1] * inv,
                           e[4 * c + 2] * inv, e[4 * c + 3] * inv);
        *(f4*)(qn + (size_t)row * LPn + 4 * c) = v;
    }
    #pragma unroll
    for (int l = 0; l < Ln; ++l) {
        float qv = e[l] * inv;
        unsigned short h = f2bf_rne(qv);
        qTnh[(size_t)l * VPn + row] = h;
        qTnl[(size_t)l * VPn + row] = f2bf_rne(qv - bf2f(h));
    }
    if (last) {
        #pragma unroll
        for (int l = 0; l < Ln; ++l) outp[(size_t)row * Ln + l] = e[l] * inv;
    }
}

// ---------------- host launcher ----------------
extern "C" void kernel_launch(void* const* d_in, const int* in_sizes, int n_in,
                              void* d_out, int out_size, void* d_ws, size_t ws_size,
                              hipStream_t stream) {
    const float* didx   = (const float*)d_in[0];
    const float* coords = (const float*)d_in[1];
    const float* Fw     = (const float*)d_in[2];
    const float* Sw     = (const float*)d_in[3];
    const float* Cm     = (const float*)d_in[4];
    float* outp = (float*)d_out;
    float* wsf = (float*)d_ws;

    int*   flags = (int*)wsf;                           // 16 floats reserved
    float* diagS = wsf + 16;                            // VPn
    float* xyz   = diagS + VPn;                         // VPn*4
    float* U     = xyz + (size_t)VPn * 4;               // VPn*48
    float* qA    = U + (size_t)VPn * LPn;
    float* qB    = qA + (size_t)VPn * LPn;
    float* phi   = qB + (size_t)VPn * LPn;
    float* phi2  = phi + (size_t)VPn * LPn;
    unsigned short* qTAh = (unsigned short*)(phi2 + (size_t)VPn * LPn);
    unsigned short* qTAl = qTAh + (size_t)LPn * VPn;
    unsigned short* qTBh = qTAl + (size_t)LPn * VPn;
    unsigned short* qTBl = qTBh + (size_t)LPn * VPn;
    float* part  = (float*)(qTBl + (size_t)LPn * VPn);  // NS*48*VPn

    size_t base_f = 16 + (size_t)VPn * (1 + 4) + (size_t)VPn * LPn * 5 + (size_t)VPn * LPn * 2;
    int NS = 9;                                         // 162 tiles = 9*18 exactly; 738 blocks ~ 0.96*3/CU
    while (NS > 1 && (base_f + (size_t)NS * LPn * VPn) * 4 > ws_size) NS--;
    int jchunkF = (((JPAD / 64) + NS - 1) / NS) * 64;
    int jchunkG = (((Vn + NS - 1) / NS) + 31) & ~31;

    hipMemsetAsync(flags, 0, 16, stream);
    hipLaunchKernelGGL(k_detect, dim3((Vn / 2 + 255) / 256, 1024), dim3(256), 0, stream,
                       Fw, Sw, flags, diagS);
    hipLaunchKernelGGL(k_detC, dim3(1), dim3(256), 0, stream, Cm, flags);
    hipLaunchKernelGGL(k_initU, dim3(RBn), dim3(256), 0, stream,
                       didx, coords, U, qA, qB, qTAh, qTAl, qTBh, qTBl, xyz);

    float* qcur = qA;  float* qnxt = qB;
    unsigned short* qThc = qTAh;  unsigned short* qTlc = qTAl;
    unsigned short* qThn = qTBh;  unsigned short* qTln = qTBl;
    for (int it = 0; it < NITER; ++it) {
        hipLaunchKernelGGL(k_phi, dim3(VPn / BR, NS), dim3(256), 0, stream,
                           qThc, qTlc, (const f4*)xyz, Fw, qcur, part, flags,
                           jchunkF, jchunkG);
        hipLaunchKernelGGL(k_R0, dim3(LPn * (VPn / 4) / 256), dim3(256), 0, stream,
                           part, qThc, qTlc, phi, flags, NS, 0);
        hipLaunchKernelGGL(k_sp, dim3(RBn, NS), dim3(256), 0, stream,
                           Sw, phi, part, flags, jchunkG);
        hipLaunchKernelGGL(k_R0, dim3(LPn * (VPn / 4) / 256), dim3(256), 0, stream,
                           part, qThc, qTlc, phi2, flags, NS, 1);
        hipLaunchKernelGGL(k_B, dim3(RBn), dim3(256), 0, stream,
                           U, phi, phi2, diagS, Cm, Fw, flags,
                           qnxt, qThn, qTln, outp, (it == NITER - 1) ? 1 : 0);
        float* tq = qcur; qcur = qnxt; qnxt = tq;
        unsigned short* th = qThc; qThc = qThn; qThn = th;
        unsigned short* tl = qTlc; qTlc = qTln; qTln = tl;
    }
}

// Round 8
// 577.958 us; speedup vs baseline: 1.5606x; 1.0202x over previous
//
#include <hip/hip_runtime.h>
#include <stdint.h>

#define Vn 10242
#define Ln 42
#define LPn 48
#define VPn 10496    /* 41*256 = 82*128 padded rows */
#define RBn 41
#define JPAD 10368   /* 162*64 : j range padded to K-tile multiple */
#define NITER 5
#define SCL 1.69864360f  /* sqrt(2*log2(e)) : exp(-2 d^2) == exp2(-|SCL*dx|^2) */
#define BR 128

typedef float4 f4;
typedef short bf16x8 __attribute__((ext_vector_type(8)));
typedef float f32x4 __attribute__((ext_vector_type(4)));
typedef unsigned u32x4 __attribute__((ext_vector_type(4)));

__device__ __forceinline__ unsigned cvtpk_bf16(float a, float b) {
    unsigned r;
    asm("v_cvt_pk_bf16_f32 %0, %1, %2" : "=v"(r) : "v"(a), "v"(b));
    return r;  // lo16 = bf16(a), hi16 = bf16(b)
}
__device__ __forceinline__ unsigned short f2bf_rne(float f) {
    unsigned u = __float_as_uint(f);
    u = (u + 0x7fffu + ((u >> 16) & 1u)) >> 16;
    return (unsigned short)u;
}
__device__ __forceinline__ float bf2f(unsigned short h) {
    return __uint_as_float(((unsigned)h) << 16);
}

// ---------------- structure detection: F uniform? S diagonal? diag(S) ----------------
__global__ __launch_bounds__(256) void k_detect(const float* __restrict__ F,
                                                const float* __restrict__ S,
                                                int* flags, float* __restrict__ diagS) {
    int jj = blockIdx.x * 256 + threadIdx.x;          // float2 column index
    if (jj >= Vn / 2) return;
    int j = jj * 2;
    const float c0 = F[0];
    int violF = 0, violS = 0;
    for (int i = blockIdx.y; i < Vn; i += (int)gridDim.y) {
        size_t off = (size_t)i * Vn + j;
        float2 f = *(const float2*)(F + off);
        float2 s = *(const float2*)(S + off);
        violF |= (f.x != c0) | (f.y != c0);
        if (i == j)          { diagS[j] = s.x;     violS |= (s.y != 0.0f); }
        else if (i == j + 1) { diagS[j + 1] = s.y; violS |= (s.x != 0.0f); }
        else                 violS |= (s.x != 0.0f) | (s.y != 0.0f);
    }
    if (violF) atomicOr(&flags[0], 1);
    if (violS) atomicOr(&flags[1], 1);
}

// ---------------- C identity? ----------------
__global__ void k_detC(const float* __restrict__ Cm, int* flags) {
    int viol = 0;
    for (int idx = threadIdx.x; idx < Ln * Ln; idx += 256) {
        int r = idx / Ln, c = idx - r * Ln;
        float expct = (r == c) ? 1.0f : 0.0f;
        viol |= (Cm[idx] != expct);
    }
    if (viol) atomicOr(&flags[3], 1);
}

// ---------------- U, q0 = softmax(U), scaled coords, qT hi/lo bf16; zero pads ----------------
__global__ __launch_bounds__(256) void k_initU(const float* __restrict__ didx,
                                               const float* __restrict__ coords,
                                               float* __restrict__ U, float* __restrict__ qA,
                                               float* __restrict__ qB,
                                               unsigned short* __restrict__ qTAh,
                                               unsigned short* __restrict__ qTAl,
                                               unsigned short* __restrict__ qTBh,
                                               unsigned short* __restrict__ qTBl,
                                               float* __restrict__ xyz) {
    int row = blockIdx.x * 256 + threadIdx.x;   // covers [0, VPn)
    if (row >= Vn) {
        #pragma unroll
        for (int l = 0; l < LPn; ++l) {
            U[(size_t)row * LPn + l] = 0.0f;
            qA[(size_t)row * LPn + l] = 0.0f;
            qB[(size_t)row * LPn + l] = 0.0f;
            qTAh[(size_t)l * VPn + row] = 0;
            qTAl[(size_t)l * VPn + row] = 0;
            qTBh[(size_t)l * VPn + row] = 0;
            qTBl[(size_t)l * VPn + row] = 0;
        }
        *(f4*)(xyz + (size_t)row * 4) = make_float4(0.f, 0.f, 0.f, 0.f);
        return;
    }
    float ux = SCL * coords[(size_t)row * 3 + 0];
    float uy = SCL * coords[(size_t)row * 3 + 1];
    float uz = SCL * coords[(size_t)row * 3 + 2];
    float ss = ux * ux + uy * uy + uz * uz;
    *(f4*)(xyz + (size_t)row * 4) = make_float4(ux, uy, uz, ss);
    float u[Ln];
    float mx = -3.0e38f;
    #pragma unroll
    for (int l = 0; l < Ln; ++l) {
        float x = didx[(size_t)row * Ln + l];
        x = fminf(fmaxf(x, 1e-6f), 1.0f);
        u[l] = __logf(x);
        mx = fmaxf(mx, u[l]);
    }
    float s = 0.0f;
    float e[Ln];
    #pragma unroll
    for (int l = 0; l < Ln; ++l) { e[l] = __expf(u[l] - mx); s += e[l]; }
    float inv = 1.0f / s;
    #pragma unroll
    for (int l = 0; l < Ln; ++l) {
        float qv = e[l] * inv;
        unsigned short h = f2bf_rne(qv);
        U[(size_t)row * LPn + l] = u[l];
        qA[(size_t)row * LPn + l] = qv;
        qTAh[(size_t)l * VPn + row] = h;
        qTAl[(size_t)l * VPn + row] = f2bf_rne(qv - bf2f(h));
    }
    #pragma unroll
    for (int l = Ln; l < LPn; ++l) {
        U[(size_t)row * LPn + l] = 0.0f;
        qA[(size_t)row * LPn + l] = 0.0f;
        qB[(size_t)row * LPn + l] = 0.0f;
        qTAh[(size_t)l * VPn + row] = 0;
        qTAl[(size_t)l * VPn + row] = 0;
        qTBh[(size_t)l * VPn + row] = 0;  // k_B never writes pad labels
        qTBl[(size_t)l * VPn + row] = 0;
    }
}

// ---------------- shared union: fast B tiles | general W tile ----------------
union ShPhi {
    struct {
        uint4 Bh[LPn][8];     // 6 KB
        uint4 Bl[LPn][8];     // 6 KB
    } f;
    float w[256][33];         // 33.8 KB (general path)
};

// ---------------- general tiled body: partials = (W [*G]) @ X ----------------
template <int USEG>
__device__ __forceinline__ void mat_gen_body(const float* __restrict__ W,
                                             const float* __restrict__ X,
                                             const float* __restrict__ xyz,
                                             float* __restrict__ part, int jchunk,
                                             ShPhi& sh) {
    int t = threadIdx.x;
    int row = blockIdx.x * 256 + t;
    bool act = (row < Vn);
    int j0 = blockIdx.y * jchunk;
    int j1 = j0 + jchunk; if (j1 > Vn) j1 = Vn;
    f4 xi = make_float4(0.f, 0.f, 0.f, 0.f);
    if (USEG && act) xi = *(const f4*)(xyz + (size_t)row * 4);
    f4 acc[12];
    #pragma unroll
    for (int c = 0; c < 12; ++c) acc[c] = make_float4(0.f, 0.f, 0.f, 0.f);
    for (int jt = j0; jt < j1; jt += 32) {
        __syncthreads();
        #pragma unroll
        for (int k = 0; k < 8; ++k) {
            int idx = t + k * 256;
            int r = idx >> 3;
            int cc = (idx & 7) << 2;
            int rr = blockIdx.x * 256 + r;
            int jc = jt + cc;
            float v0 = 0.f, v1 = 0.f, v2 = 0.f, v3 = 0.f;
            if (rr < Vn) {
                const float* wp = W + (size_t)rr * Vn + jc;
                if (jc + 0 < Vn) v0 = wp[0];
                if (jc + 1 < Vn) v1 = wp[1];
                if (jc + 2 < Vn) v2 = wp[2];
                if (jc + 3 < Vn) v3 = wp[3];
            }
            sh.w[r][cc + 0] = v0; sh.w[r][cc + 1] = v1;
            sh.w[r][cc + 2] = v2; sh.w[r][cc + 3] = v3;
        }
        __syncthreads();
        int jend = j1 - jt; if (jend > 32) jend = 32;
        for (int jj = 0; jj < jend; ++jj) {
            int j = jt + jj;
            float f = sh.w[t][jj];
            if (USEG) {
                f4 xj = *(const f4*)(xyz + (size_t)j * 4);
                float dx = xi.x - xj.x, dy = xi.y - xj.y, dz = xi.z - xj.z;
                float t2 = dx * dx; t2 = fmaf(dy, dy, t2); t2 = fmaf(dz, dz, t2);
                float w = exp2f(-t2);
                w = (j == row) ? 0.0f : w;
                f *= w;
            }
            const f4* qr = (const f4*)(X + (size_t)j * LPn);
            #pragma unroll
            for (int c = 0; c < 12; ++c) {
                f4 qv = qr[c];
                acc[c].x = fmaf(f, qv.x, acc[c].x);
                acc[c].y = fmaf(f, qv.y, acc[c].y);
                acc[c].z = fmaf(f, qv.z, acc[c].z);
                acc[c].w = fmaf(f, qv.w, acc[c].w);
            }
        }
    }
    size_t base = (size_t)blockIdx.y * LPn * VPn + row;
    if (act) {
        #pragma unroll
        for (int c = 0; c < 12; ++c) {
            part[base + (size_t)(4 * c + 0) * VPn] = acc[c].x;
            part[base + (size_t)(4 * c + 1) * VPn] = acc[c].y;
            part[base + (size_t)(4 * c + 2) * VPn] = acc[c].z;
            part[base + (size_t)(4 * c + 3) * VPn] = acc[c].w;
        }
    } else if (row < VPn) {
        #pragma unroll
        for (int c = 0; c < LPn; ++c) part[base + (size_t)c * VPn] = 0.0f;
    }
}

// ---------------- filter pass: fast (reg-A + LDS-B, r7 staging) or general ----------------
__global__ __launch_bounds__(256, 3) void k_phi(const unsigned short* __restrict__ qTh,
                                                const unsigned short* __restrict__ qTl,
                                                const f4* __restrict__ xyz4,
                                                const float* __restrict__ Fw,
                                                const float* __restrict__ q,
                                                float* __restrict__ part,
                                                const int* __restrict__ flags,
                                                int jchunkF, int jchunkG) {
    __shared__ ShPhi sh;
    if (flags[0]) {                               // general F path
        if (blockIdx.x >= RBn) return;
        mat_gen_body<1>(Fw, q, (const float*)xyz4, part, jchunkG, sh);
        return;
    }
    const int t = threadIdx.x;
    const int lane = t & 63;
    const int wv = t >> 6;
    const int lo16 = lane & 15, hi4 = lane >> 4;
    const int rowbase = blockIdx.x * BR;
    const int i0 = rowbase + wv * 32 + lo16;      // this lane's A rows (r5-validated mapping)
    const int i1 = i0 + 16;
    f4 p0 = xyz4[i0];
    f4 p1 = xyz4[i1];
    const float a0x = 2.f * p0.x, a0y = 2.f * p0.y, a0z = 2.f * p0.z, c0 = -p0.w;
    const float a1x = 2.f * p1.x, a1y = 2.f * p1.y, a1z = 2.f * p1.z, c1 = -p1.w;
    f32x4 acc[2][3];
    #pragma unroll
    for (int rs = 0; rs < 2; ++rs)
        #pragma unroll
        for (int cs = 0; cs < 3; ++cs) acc[rs][cs] = (f32x4){0.f, 0.f, 0.f, 0.f};
    const int j0 = blockIdx.y * jchunkF;
    int j1 = j0 + jchunkF; if (j1 > JPAD) j1 = JPAD;
    const int n0 = t >> 3, sl0 = t & 7;
    const int s1 = t + 256;
    const int n1 = s1 >> 3, sl1 = s1 & 7;
    const bool has1 = (s1 < LPn * 8);
    for (int jt = j0; jt < j1; jt += 64) {
        // --- B-tile prefetch into regs (coalesced; latency hides under w-gen) ---
        uint4 bh0 = *(const uint4*)(qTh + (size_t)n0 * VPn + jt + sl0 * 8);
        uint4 bl0 = *(const uint4*)(qTl + (size_t)n0 * VPn + jt + sl0 * 8);
        uint4 bh1, bl1;
        if (has1) {
            bh1 = *(const uint4*)(qTh + (size_t)n1 * VPn + jt + sl1 * 8);
            bl1 = *(const uint4*)(qTl + (size_t)n1 * VPn + jt + sl1 * 8);
        }
        // --- w-gen directly into this lane's A-fragments (no LDS round trip) ---
        unsigned AH[2][2][4], AL[2][2][4];        // [kk][rowset][reg]
        #pragma unroll
        for (int kk = 0; kk < 2; ++kk) {
            const int jb = jt + kk * 32 + hi4 * 8;
            float w0[8], w1[8];
            #pragma unroll
            for (int m = 0; m < 8; ++m) {
                f4 xj = xyz4[jb + m];             // 16 lanes share each address
                w0[m] = exp2f(fmaf(a0z, xj.z, fmaf(a0y, xj.y, fmaf(a0x, xj.x, c0 - xj.w))));
                w1[m] = exp2f(fmaf(a1z, xj.z, fmaf(a1y, xj.y, fmaf(a1x, xj.x, c1 - xj.w))));
            }
            #pragma unroll
            for (int m = 0; m < 4; ++m) {
                unsigned hh0 = cvtpk_bf16(w0[2 * m], w0[2 * m + 1]);
                unsigned hh1 = cvtpk_bf16(w1[2 * m], w1[2 * m + 1]);
                AH[kk][0][m] = hh0;
                AH[kk][1][m] = hh1;
                AL[kk][0][m] = cvtpk_bf16(w0[2 * m]     - __uint_as_float(hh0 << 16),
                                          w0[2 * m + 1] - __uint_as_float(hh0 & 0xffff0000u));
                AL[kk][1][m] = cvtpk_bf16(w1[2 * m]     - __uint_as_float(hh1 << 16),
                                          w1[2 * m + 1] - __uint_as_float(hh1 & 0xffff0000u));
            }
        }
        __syncthreads();   // previous tile's B reads done
        sh.f.Bh[n0][sl0 ^ (n0 & 7)] = bh0;
        sh.f.Bl[n0][sl0 ^ (n0 & 7)] = bl0;
        if (has1) {
            sh.f.Bh[n1][sl1 ^ (n1 & 7)] = bh1;
            sh.f.Bl[n1][sl1 ^ (n1 & 7)] = bl1;
        }
        __syncthreads();   // B tile ready
        #pragma unroll
        for (int kk = 0; kk < 2; ++kk) {
            union Uu { u32x4 u; bf16x8 v; };
            Uu A0h, A0l, A1h, A1l;
            A0h.u = (u32x4){AH[kk][0][0], AH[kk][0][1], AH[kk][0][2], AH[kk][0][3]};
            A1h.u = (u32x4){AH[kk][1][0], AH[kk][1][1], AH[kk][1][2], AH[kk][1][3]};
            A0l.u = (u32x4){AL[kk][0][0], AL[kk][0][1], AL[kk][0][2], AL[kk][0][3]};
            A1l.u = (u32x4){AL[kk][1][0], AL[kk][1][1], AL[kk][1][2], AL[kk][1][3]};
            #pragma unroll
            for (int cs = 0; cs < 3; ++cs) {
                int n = cs * 16 + lo16;
                int slot = (kk * 4 + hi4) ^ (n & 7);
                bf16x8 bh = *(bf16x8*)&sh.f.Bh[n][slot];
                bf16x8 bl = *(bf16x8*)&sh.f.Bl[n][slot];
                // 3-product double-bf16 (lo*lo dropped: |err| ~2^-18)
                acc[0][cs] = __builtin_amdgcn_mfma_f32_16x16x32_bf16(A0h.v, bh, acc[0][cs], 0, 0, 0);
                acc[0][cs] = __builtin_amdgcn_mfma_f32_16x16x32_bf16(A0h.v, bl, acc[0][cs], 0, 0, 0);
                acc[0][cs] = __builtin_amdgcn_mfma_f32_16x16x32_bf16(A0l.v, bh, acc[0][cs], 0, 0, 0);
                acc[1][cs] = __builtin_amdgcn_mfma_f32_16x16x32_bf16(A1h.v, bh, acc[1][cs], 0, 0, 0);
                acc[1][cs] = __builtin_amdgcn_mfma_f32_16x16x32_bf16(A1h.v, bl, acc[1][cs], 0, 0, 0);
                acc[1][cs] = __builtin_amdgcn_mfma_f32_16x16x32_bf16(A1l.v, bh, acc[1][cs], 0, 0, 0);
            }
        }
    }
    size_t pb = (size_t)blockIdx.y * LPn * VPn;
    #pragma unroll
    for (int rs = 0; rs < 2; ++rs)
        #pragma unroll
        for (int cs = 0; cs < 3; ++cs) {
            int col = cs * 16 + lo16;
            int row = rowbase + wv * 32 + rs * 16 + hi4 * 4;
            *(f4*)(part + pb + (size_t)col * VPn + row) =
                make_float4(acc[rs][cs][0], acc[rs][cs][1], acc[rs][cs][2], acc[rs][cs][3]);
        }
}

// ---------------- general spatial pass: part = S @ phi ----------------
__global__ __launch_bounds__(256) void k_sp(const float* __restrict__ Sw,
                                            const float* __restrict__ phi,
                                            float* __restrict__ part,
                                            const int* __restrict__ flags, int jchunk) {
    if (!flags[1]) return;
    __shared__ ShPhi sh;
    mat_gen_body<0>(Sw, phi, (const float*)nullptr, part, jchunk, sh);
}

// ---------------- reduce partials -> phi [row][48]; bf16-exact diagonal subtract ----------------
__global__ __launch_bounds__(256) void k_R0(const float* __restrict__ part,
                                            const unsigned short* __restrict__ qTh,
                                            const unsigned short* __restrict__ qTl,
                                            float* __restrict__ phi,
                                            const int* __restrict__ flags,
                                            int NS, int gate) {
    if (gate && !flags[1]) return;
    int tg = blockIdx.x * 256 + threadIdx.x;       // 492*256 == 48 * (VPn/4)
    int c = tg / (VPn / 4);
    int r4 = (tg - c * (VPn / 4)) * 4;
    f4 s = make_float4(0.f, 0.f, 0.f, 0.f);
    for (int n = 0; n < NS; ++n) {
        f4 v = *(const f4*)(part + ((size_t)n * LPn + c) * VPn + r4);
        s.x += v.x; s.y += v.y; s.z += v.z; s.w += v.w;
    }
    if (!gate && !flags[0]) {                      // MFMA path included diagonal w=1
        ushort4 h = *(const ushort4*)(qTh + (size_t)c * VPn + r4);
        ushort4 l = *(const ushort4*)(qTl + (size_t)c * VPn + r4);
        s.x -= bf2f(h.x) + bf2f(l.x);
        s.y -= bf2f(h.y) + bf2f(l.y);
        s.z -= bf2f(h.z) + bf2f(l.z);
        s.w -= bf2f(h.w) + bf2f(l.w);
    }
    phi[(size_t)(r4 + 0) * LPn + c] = s.x;
    phi[(size_t)(r4 + 1) * LPn + c] = s.y;
    phi[(size_t)(r4 + 2) * LPn + c] = s.z;
    phi[(size_t)(r4 + 3) * LPn + c] = s.w;
}

// ---------------- epilogue: logits = U + scale*(pt [@C]); q = softmax; emit q + qT hi/lo ----------------
__global__ __launch_bounds__(64) void k_B(const float* __restrict__ U,
                                          const float* __restrict__ phi,
                                          const float* __restrict__ phi2,
                                          const float* __restrict__ diagS,
                                          const float* __restrict__ Cm,
                                          const float* __restrict__ Fw,
                                          const int* __restrict__ flags,
                                          float* __restrict__ qn,
                                          unsigned short* __restrict__ qTnh,
                                          unsigned short* __restrict__ qTnl,
                                          float* __restrict__ outp, int last) {
    __shared__ float ldsC[Ln][LPn];
    int t = threadIdx.x;
    if (flags[3]) {
        for (int idx = t; idx < Ln * LPn; idx += 64) {
            int m = idx / LPn, l = idx - m * LPn;
            ldsC[m][l] = (l < Ln) ? Cm[(size_t)m * Ln + l] : 0.0f;
        }
    }
    __syncthreads();
    int row = blockIdx.x * 64 + t;
    if (row >= Vn) return;
    const float* src = flags[1] ? phi2 : phi;
    float pt[LPn];
    #pragma unroll
    for (int c = 0; c < 12; ++c) {
        f4 v = *(const f4*)(src + (size_t)row * LPn + 4 * c);
        pt[4 * c + 0] = v.x; pt[4 * c + 1] = v.y;
        pt[4 * c + 2] = v.z; pt[4 * c + 3] = v.w;
    }
    float scale = (flags[0] ? 1.0f : Fw[0]) * (flags[1] ? 1.0f : diagS[row]);
    float ph[LPn];
    if (flags[3]) {
        #pragma unroll
        for (int c = 0; c < LPn; ++c) ph[c] = 0.f;
        #pragma unroll
        for (int m = 0; m < Ln; ++m) {
            float pm = pt[m];
            #pragma unroll
            for (int c = 0; c < 12; ++c) {
                f4 cv = *(const f4*)&ldsC[m][4 * c];
                ph[4 * c + 0] = fmaf(pm, cv.x, ph[4 * c + 0]);
                ph[4 * c + 1] = fmaf(pm, cv.y, ph[4 * c + 1]);
                ph[4 * c + 2] = fmaf(pm, cv.z, ph[4 * c + 2]);
                ph[4 * c + 3] = fmaf(pm, cv.w, ph[4 * c + 3]);
            }
        }
    } else {
        #pragma unroll
        for (int c = 0; c < LPn; ++c) ph[c] = pt[c];
    }
    float lg[LPn];
    #pragma unroll
    for (int c = 0; c < 12; ++c) {
        f4 uv = *(const f4*)(U + (size_t)row * LPn + 4 * c);
        lg[4 * c + 0] = uv.x + scale * ph[4 * c + 0];
        lg[4 * c + 1] = uv.y + scale * ph[4 * c + 1];
        lg[4 * c + 2] = uv.z + scale * ph[4 * c + 2];
        lg[4 * c + 3] = uv.w + scale * ph[4 * c + 3];
    }
    float mx = lg[0];
    #pragma unroll
    for (int l = 1; l < Ln; ++l) mx = fmaxf(mx, lg[l]);
    float s = 0.f;
    float e[LPn];
    #pragma unroll
    for (int l = 0; l < Ln; ++l) { e[l] = __expf(lg[l] - mx); s += e[l]; }
    #pragma unroll
    for (int l = Ln; l < LPn; ++l) e[l] = 0.f;
    float inv = 1.0f / s;
    #pragma unroll
    for (int c = 0; c < 12; ++c) {
        f4 v = make_float4(e[4 * c + 0] * inv, e[4 * c + 1] * inv,
                           e[4 * c + 2] * inv, e[4 * c + 3] * inv);
        *(f4*)(qn + (size_t)row * LPn + 4 * c) = v;
    }
    #pragma unroll
    for (int l = 0; l < Ln; ++l) {
        float qv = e[l] * inv;
        unsigned short h = f2bf_rne(qv);
        qTnh[(size_t)l * VPn + row] = h;
        qTnl[(size_t)l * VPn + row] = f2bf_rne(qv - bf2f(h));
    }
    if (last) {
        #pragma unroll
        for (int l = 0; l < Ln; ++l) outp[(size_t)row * Ln + l] = e[l] * inv;
    }
}

// ---------------- host launcher ----------------
extern "C" void kernel_launch(void* const* d_in, const int* in_sizes, int n_in,
                              void* d_out, int out_size, void* d_ws, size_t ws_size,
                              hipStream_t stream) {
    const float* didx   = (const float*)d_in[0];
    const float* coords = (const float*)d_in[1];
    const float* Fw     = (const float*)d_in[2];
    const float* Sw     = (const float*)d_in[3];
    const float* Cm     = (const float*)d_in[4];
    float* outp = (float*)d_out;
    float* wsf = (float*)d_ws;

    int*   flags = (int*)wsf;                           // 16 floats reserved
    float* diagS = wsf + 16;                            // VPn
    float* xyz   = diagS + VPn;                         // VPn*4
    float* U     = xyz + (size_t)VPn * 4;               // VPn*48
    float* qA    = U + (size_t)VPn * LPn;
    float* qB    = qA + (size_t)VPn * LPn;
    float* phi   = qB + (size_t)VPn * LPn;
    float* phi2  = phi + (size_t)VPn * LPn;
    unsigned short* qTAh = (unsigned short*)(phi2 + (size_t)VPn * LPn);
    unsigned short* qTAl = qTAh + (size_t)LPn * VPn;
    unsigned short* qTBh = qTAl + (size_t)LPn * VPn;
    unsigned short* qTBl = qTBh + (size_t)LPn * VPn;
    float* part  = (float*)(qTBl + (size_t)LPn * VPn);  // NS*48*VPn

    size_t base_f = 16 + (size_t)VPn * (1 + 4) + (size_t)VPn * LPn * 5 + (size_t)VPn * LPn * 2;
    int NS = 9;                                         // 162 tiles = 9*18 exactly
    while (NS > 1 && (base_f + (size_t)NS * LPn * VPn) * 4 > ws_size) NS--;
    int jchunkF = (((JPAD / 64) + NS - 1) / NS) * 64;
    int jchunkG = (((Vn + NS - 1) / NS) + 31) & ~31;

    hipMemsetAsync(flags, 0, 16, stream);
    hipLaunchKernelGGL(k_detect, dim3((Vn / 2 + 255) / 256, 1024), dim3(256), 0, stream,
                       Fw, Sw, flags, diagS);
    hipLaunchKernelGGL(k_detC, dim3(1), dim3(256), 0, stream, Cm, flags);
    hipLaunchKernelGGL(k_initU, dim3(RBn), dim3(256), 0, stream,
                       didx, coords, U, qA, qB, qTAh, qTAl, qTBh, qTBl, xyz);

    float* qcur = qA;  float* qnxt = qB;
    unsigned short* qThc = qTAh;  unsigned short* qTlc = qTAl;
    unsigned short* qThn = qTBh;  unsigned short* qTln = qTBl;
    for (int it = 0; it < NITER; ++it) {
        hipLaunchKernelGGL(k_phi, dim3(VPn / BR, NS), dim3(256), 0, stream,
                           qThc, qTlc, (const f4*)xyz, Fw, qcur, part, flags,
                           jchunkF, jchunkG);
        hipLaunchKernelGGL(k_R0, dim3(LPn * (VPn / 4) / 256), dim3(256), 0, stream,
                           part, qThc, qTlc, phi, flags, NS, 0);
        hipLaunchKernelGGL(k_sp, dim3(RBn, NS), dim3(256), 0, stream,
                           Sw, phi, part, flags, jchunkG);
        hipLaunchKernelGGL(k_R0, dim3(LPn * (VPn / 4) / 256), dim3(256), 0, stream,
                           part, qThc, qTlc, phi2, flags, NS, 1);
        hipLaunchKernelGGL(k_B, dim3(VPn / 64), dim3(64), 0, stream,
                           U, phi, phi2, diagS, Cm, Fw, flags,
                           qnxt, qThn, qTln, outp, (it == NITER - 1) ? 1 : 0);
        float* tq = qcur; qcur = qnxt; qnxt = tq;
        unsigned short* th = qThc; qThc = qThn; qThn = th;
        unsigned short* tl = qTlc; qTlc = qTln; qTln = tl;
    }
}